// Round 6
// baseline (132.733 us; speedup 1.0000x reference)
//
#include <hip/hip_runtime.h>
#include <cstdint>
#include <cstddef>

// Problem constants (B=8, H=W=1024)
#define N_PIX   1048576
#define B_ROWS  8
#define K_ALL   524288          // max(1, int(N*0.5))
#define LOSS_BLOCKS 2048        // k_loss: 256/row, 4096 px/block
#define LOSS_STAGES 4           // quads per thread, depth-1 pipelined
#define HIST_BLOCKS 1024        // k_hist: 128/row, 8192 px/block
#define HPT     4               // uint4 (8 px) per thread in k_hist
#define NBINS   1024            // bins of width 1/128 on [0,8): bin = fx >> 6
#define NCOPY   8               // hist copies (XCD-private under round-robin)
#define CSHIFT  42              // u64 = (count << 42) | fixed_sum(2^-13)
#define SUMMASK ((1ull << CSHIFT) - 1ull)
#define FXSCALE 8192.0f         // 2^13 fixed-point for u16 packed loss

// R6 structural split (after 5 fused-pass1 theories all landed ~38-41us with
// no counter saturated): separate the STREAM from the HISTOGRAM so rocprof
// gives per-phase rows permanently.
//   k_loss: 96MB in -> BCE -> 16.8MB u16 fx out (sentinel 0xFFFF = skip),
//           npos/spos partials. No LDS, no atomics, branchless stores.
//   k_hist: 16.8MB in (L2/L3-warm) -> LDS hist -> XCD-private global copies.
//   k_final: selection from hist copies (scale 2^-13), unchanged logic.
// Precision: fx rounding |err|<=6e-5/elem << 1.6e-2 tol; threshold-bin
// interpolation (width 1/128) unchanged from verified rounds.
// Packing margins: per-(row,copy) count <= 1.05M < 2^22; fixed sum <=
// 1.05M*46700 = 4.9e10 < 2^42. Block-local far smaller.
// R1 lesson stands: no single-kernel fusion (threadfence = L2 wb storm).

// ---------- K1: pure-stream loss kernel ----------
__global__ __launch_bounds__(256) void k_loss(
    const float4* __restrict__ lg, const int4* __restrict__ tg, const int4* __restrict__ mk,
    uint4* __restrict__ fxout,
    unsigned* __restrict__ partNpos, double* __restrict__ partSpos, float* __restrict__ out)
{
    __shared__ unsigned swp[4];
    __shared__ double   sws[4];
    const int tid = threadIdx.x;
    if (blockIdx.x == 0 && tid == 0) *out = 0.f;   // k_final (later dispatch) accumulates

    const size_t qbase = (size_t)blockIdx.x * (LOSS_STAGES * 256) + tid;

    unsigned npos = 0; float spos = 0.f;

    auto bcefx = [&](float xx, int tt, int mm) -> unsigned {
        float ax = fabsf(xx);
        float e = __expf(-ax);
        float l = __logf(1.f + e);
        float bce = fmaxf(xx, 0.f) - xx * (float)tt + l;
        unsigned fx = __float2uint_rn(bce * FXSCALE);
        if (fx > 0xFFFEu) fx = 0xFFFEu;            // never hit (bce < 8) but safe
        if (mm && tt) { npos++; spos += bce; }
        return (mm && !tt) ? fx : 0xFFFFu;         // sentinel: not a kept-negative
    };

    // depth-1 software pipeline (R5 pattern); regs only, compile-time indexed
    float4 x[2]; int4 t[2]; int4 m[2];
    x[0] = lg[qbase]; t[0] = tg[qbase]; m[0] = mk[qbase];
    uint4 acc;
    #pragma unroll
    for (int j = 0; j < LOSS_STAGES; ++j) {
        const int cur = j & 1, nxt = cur ^ 1;
        if (j < LOSS_STAGES - 1) {
            const size_t q = qbase + (size_t)(j + 1) * 256;
            x[nxt] = lg[q]; t[nxt] = tg[q]; m[nxt] = mk[q];
        }
        __builtin_amdgcn_sched_barrier(0);   // loads stay above, compute below
        unsigned f0 = bcefx(x[cur].x, t[cur].x, m[cur].x);
        unsigned f1 = bcefx(x[cur].y, t[cur].y, m[cur].y);
        unsigned f2 = bcefx(x[cur].z, t[cur].z, m[cur].z);
        unsigned f3 = bcefx(x[cur].w, t[cur].w, m[cur].w);
        if ((j & 1) == 0) {
            acc.x = f0 | (f1 << 16); acc.y = f2 | (f3 << 16);
        } else {
            acc.z = f0 | (f1 << 16); acc.w = f2 | (f3 << 16);
            // coalesced 16B store; block stride = 2*256 uint4
            fxout[(size_t)blockIdx.x * (2 * 256) + (size_t)(j >> 1) * 256 + tid] = acc;
        }
    }

    // block-level reduce of npos/sumPos -> per-block partials
    for (int o = 32; o; o >>= 1) {
        npos += __shfl_down(npos, o);
        spos += __shfl_down(spos, o);
    }
    if ((tid & 63) == 0) { swp[tid >> 6] = npos; sws[tid >> 6] = (double)spos; }
    __syncthreads();
    if (tid == 0) {
        partNpos[blockIdx.x] = swp[0] + swp[1] + swp[2] + swp[3];
        partSpos[blockIdx.x] = sws[0] + sws[1] + sws[2] + sws[3];
    }
}

// ---------- K2: histogram of packed fx (isolated atomic cost) ----------
__global__ __launch_bounds__(256) void k_hist(
    const uint4* __restrict__ fx4, unsigned long long* __restrict__ hist)
{
    __shared__ unsigned long long hq[NBINS];   // 8 KB
    const int tid = threadIdx.x;
    for (int b = tid; b < NBINS; b += 256) hq[b] = 0ull;
    __syncthreads();

    const int r = blockIdx.x >> 7;             // 128 blocks per row
    const size_t base = (size_t)blockIdx.x * (HPT * 256) + tid;

    uint4 v[HPT];
    #pragma unroll
    for (int s = 0; s < HPT; ++s) v[s] = fx4[base + (size_t)s * 256];

    #pragma unroll
    for (int s = 0; s < HPT; ++s) {
        unsigned w[4] = { v[s].x, v[s].y, v[s].z, v[s].w };
        #pragma unroll
        for (int q = 0; q < 4; ++q) {
            unsigned lo = w[q] & 0xFFFFu, hi = w[q] >> 16;
            if (lo != 0xFFFFu)
                atomicAdd(&hq[lo >> 6], (1ull << CSHIFT) | (unsigned long long)lo);
            if (hi != 0xFFFFu)
                atomicAdd(&hq[hi >> 6], (1ull << CSHIFT) | (unsigned long long)hi);
        }
    }
    __syncthreads();

    unsigned long long* gh = hist + ((size_t)r * NCOPY + (blockIdx.x & (NCOPY - 1))) * NBINS;
    for (int b = tid; b < NBINS; b += 256) {
        unsigned long long u = hq[b];
        if (u) atomicAdd(&gh[b], u);
    }
}

// ---------- K3: per-row selection from packed hist + output ----------
__global__ __launch_bounds__(256) void k_final(
    const unsigned long long* __restrict__ hist,
    const unsigned* __restrict__ partNpos, const double* __restrict__ partSpos,
    float* __restrict__ out)
{
    __shared__ unsigned sc[2][256];
    __shared__ double   sd[2][256];
    __shared__ unsigned swp[4];
    __shared__ double   sws[4];
    __shared__ unsigned rcntgt, rcnt1;
    __shared__ double rsumgt, rsum1;

    const int r = blockIdx.x, tid = threadIdx.x;
    const unsigned long long* gh = hist + (size_t)r * NCOPY * NBINS;
    const double inv = 1.0 / (double)FXSCALE;

    // reduce per-block partials (256 k_loss blocks per row)
    {
        unsigned np = partNpos[r * 256 + tid];
        double   sp = partSpos[r * 256 + tid];
        for (int o = 32; o; o >>= 1) { np += __shfl_down(np, o); sp += __shfl_down(sp, o); }
        if ((tid & 63) == 0) { swp[tid >> 6] = np; sws[tid >> 6] = sp; }
    }
    __syncthreads();
    const unsigned npos = swp[0] + swp[1] + swp[2] + swp[3];
    const double sumPos = sws[0] + sws[1] + sws[2] + sws[3];
    __syncthreads();

    // per-thread chunk of 4 bins (summed over the 8 copies), scanned high->low
    const int per = NBINS / 256;                 // 4
    const int b0 = NBINS - 1 - tid * per;
    unsigned lc[4]; double lsum[4];
    unsigned pc = 0; double ps = 0.0;
    #pragma unroll
    for (int i = 0; i < per; ++i) {
        unsigned long long v = 0ull;
        #pragma unroll
        for (int c = 0; c < NCOPY; ++c) v += gh[(size_t)c * NBINS + (b0 - i)];
        lc[i] = (unsigned)(v >> CSHIFT);
        lsum[i] = (double)(v & SUMMASK) * inv;
        pc += lc[i]; ps += lsum[i];
    }

    // inclusive Hillis-Steele scan (thread t covers bins >= NBINS - per*(t+1))
    int pp = 0;
    sc[0][tid] = pc; sd[0][tid] = ps;
    __syncthreads();
    for (int ofs = 1; ofs < 256; ofs <<= 1) {
        unsigned c = sc[pp][tid]; double s = sd[pp][tid];
        if (tid >= ofs) { c += sc[pp][tid - ofs]; s += sd[pp][tid - ofs]; }
        sc[pp ^ 1][tid] = c; sd[pp ^ 1][tid] = s;
        pp ^= 1;
        __syncthreads();
    }
    const unsigned nneg   = sc[pp][255];
    const double   sumNeg = sd[pp][255];

    long kl = (long)K_ALL - (long)npos;
    if (kl < 0) kl = 0;
    if (kl > (long)nneg) kl = (long)nneg;
    const unsigned Kneg = (unsigned)kl;

    double sum_sel = 0.0;
    if (Kneg >= nneg) {
        sum_sel = sumNeg;                        // keep-all (or Kneg==nneg==0)
    } else if (Kneg > 0) {
        // threshold bin: exactly one thread has exc < Kneg <= inc
        unsigned inc = sc[pp][tid];
        unsigned exc = inc - pc;
        double   exs = sd[pp][tid] - ps;
        if (exc < Kneg && Kneg <= inc) {
            unsigned cum = exc; double csum = exs;
            #pragma unroll
            for (int i = 0; i < per; ++i) {
                if (cum + lc[i] >= Kneg) {
                    rcntgt = cum; rsumgt = csum;
                    rcnt1 = lc[i]; rsum1 = lsum[i];        // stash: no re-read
                    break;
                }
                cum += lc[i]; csum += lsum[i];
            }
        }
        __syncthreads();
        if (tid == 0) {
            const unsigned cntT1 = rcnt1;
            const double   sumT1 = rsum1;
            const unsigned Kp = Kneg - rcntgt;   // 1..cntT1
            const double w = 1.0 / 128.0;        // bin width (64 fx units / 2^13)
            const double avg = sumT1 / (double)cntT1;
            // shifted-uniform top-Kp mean; exact when Kp == cntT1
            const double topmean = avg + 0.5 * w * (1.0 - (double)Kp / (double)cntT1);
            sum_sel = rsumgt + (double)Kp * topmean;
        }
    }

    if (tid == 0) {
        unsigned long long kk = (unsigned long long)npos + (unsigned long long)Kneg;
        double per_s = 0.0;
        if (kk > 0) per_s = (sumPos + sum_sel) / (double)kk;
        // kk==0 => no tissue => reference falls back to loss[:,0] == 0
        atomicAdd(out, (float)(per_s / (double)B_ROWS));
    }
}

// ---------- launch ----------
extern "C" void kernel_launch(void* const* d_in, const int* in_sizes, int n_in,
                              void* d_out, int out_size, void* d_ws, size_t ws_size,
                              hipStream_t stream)
{
    const float* logits = (const float*)d_in[0];
    const int*   targets = (const int*)d_in[1];
    const int*   tissue = (const int*)d_in[2];

    char* ws = (char*)d_ws;
    size_t off = 0;
    // zeroed region: packed hist copies (at ws start)
    unsigned long long* hist = (unsigned long long*)(ws + off);
    off += (size_t)B_ROWS * NCOPY * NBINS * 8;   // 512 KB
    size_t zero_size = off;
    // non-zeroed (every slot written before read)
    unsigned* partNpos = (unsigned*)(ws + off); off += (size_t)LOSS_BLOCKS * 4;
    double*   partSpos = (double*)(ws + off);   off += (size_t)LOSS_BLOCKS * 8;
    uint4*    fxout    = (uint4*)(ws + off);    off += (size_t)(B_ROWS * N_PIX / 8) * 16; // 16.8 MB

    hipMemsetAsync(ws, 0, zero_size, stream);

    k_loss<<<LOSS_BLOCKS, 256, 0, stream>>>(
        (const float4*)logits, (const int4*)targets, (const int4*)tissue,
        fxout, partNpos, partSpos, (float*)d_out);
    k_hist<<<HIST_BLOCKS, 256, 0, stream>>>((const uint4*)fxout, hist);
    k_final<<<B_ROWS, 256, 0, stream>>>(hist, partNpos, partSpos, (float*)d_out);
}

// Round 7
// 125.353 us; speedup vs baseline: 1.0589x; 1.0589x over previous
//
#include <hip/hip_runtime.h>
#include <cstdint>
#include <cstddef>

// Problem constants (B=8, H=W=1024)
#define N_PIX   1048576
#define B_ROWS  8
#define K_ALL   524288          // max(1, int(N*0.5))
#define NBLK1   512             // pass1 blocks (2/CU; LDS 45KB -> 3/CU possible)
#define BLOCKS_PER_ROW 64
#define PX_PER_BLOCK   16384
#define NT      16              // tiles per block
#define TPX     1024            // px per tile (4KB per array)
#define NSLOT   3               // LDS ring slots (3 tiles in flight)
#define NBINS   1024            // linear bins, width 1/128 on [0,8)
#define FXSHIFT 11              // bin = fx >> 11 (2^18 fixed-point -> 128 bins/unit)
#define NCOPY   8               // hist copies (XCD-private under round-robin)
#define CSHIFT  42              // u64 = (count << 42) | fixed_sum(2^-18)
#define SUMMASK ((1ull << CSHIFT) - 1ull)
#define FPSCALE 262144.0f       // 2^18 fixed-point scale for packed sums

// R6 post-mortem: split proved k_loss (pure stream, no LDS/atomics) is ~38us
// alone -> histogram was never the bottleneck; the register-destination load
// path is (compiler serializes load->wait->use per wave; R2 VGPR=28 sank the
// prefetch, R5 pipeline only +10%). R7: revert to fused structure, stage all
// three arrays via __builtin_amdgcn_global_load_lds (fire-and-forget DMA, no
// dest VGPRs, cannot be sunk). 3-slot ring, 3 tiles ahead: 9KB in flight/wave
// x 8 waves/CU = 72KB/CU >> ~10KB Little's-law need. Raw s_barrier + counted
// vmcnt(6/3/0) (T3/T4): never drain to 0 in the loop; __syncthreads only
// before first DMA and after last (vmcnt already 0 there).
// Packing margins: per-(row,copy) count <= 131072 < 2^22, fixed sum <= 2.7e11;
// summed over 8 copies: 1.05M < 2^22, 2.2e12 < 2^42. No overflow.
// R1 lesson stands: no single-kernel fusion (threadfence = L2 wb storm).

typedef __attribute__((address_space(1))) const void gvoid_t;
typedef __attribute__((address_space(3))) void lvoid_t;
__device__ __forceinline__ void dma16(const void* g, void* l) {
    // 64 lanes x 16B: per-lane global src, wave-uniform LDS dest + lane*16
    __builtin_amdgcn_global_load_lds((gvoid_t*)g, (lvoid_t*)l, 16, 0, 0);
}
#define SBAR()  __builtin_amdgcn_s_barrier()
#define SCHED() __builtin_amdgcn_sched_barrier(0)
#define WAITV(N) asm volatile("s_waitcnt vmcnt(" #N ")" ::: "memory")

// ---------- K1: DMA-staged loss + packed LDS hist + per-block npos/sumPos ----------
__global__ __launch_bounds__(256) void k_pass1(
    const float* __restrict__ lg, const int* __restrict__ tg, const int* __restrict__ mk,
    unsigned long long* __restrict__ hist,
    unsigned* __restrict__ partNpos, double* __restrict__ partSpos, float* __restrict__ out)
{
    __shared__ uint4 stage[NSLOT][3][TPX / 4];   // 3 slots x {lg,tg,mk} x 4KB = 36KB
    __shared__ unsigned long long hq[NBINS];     // 8KB
    __shared__ unsigned swp[4];
    __shared__ double   sws[4];
    const int tid = threadIdx.x;
    const int w = tid >> 6, l = tid & 63;        // wave, lane

    for (int b = tid; b < NBINS; b += 256) hq[b] = 0ull;
    if (blockIdx.x == 0 && tid == 0) *out = 0.f; // k_final (later dispatch) accumulates
    __syncthreads();                              // before any DMA: drains nothing vital

    const size_t p0 = (size_t)blockIdx.x * PX_PER_BLOCK;

    // each wave DMAs its 1KB quarter of each array's 4KB tile chunk
    auto issue = [&](int j, int s) {
        const size_t px = p0 + (size_t)j * TPX + (size_t)w * 256 + (size_t)l * 4;
        dma16(lg + px, &stage[s][0][w * 64]);
        dma16(tg + px, &stage[s][1][w * 64]);
        dma16(mk + px, &stage[s][2][w * 64]);
    };

    unsigned npos = 0; float spos = 0.f;
    auto proc = [&](unsigned xu, unsigned tt, unsigned mm) {
        float xx = __uint_as_float(xu);
        float ax = fabsf(xx);
        float e  = __expf(-ax);
        float lo = __logf(1.f + e);
        float bce = fmaxf(xx, 0.f) - xx * (float)tt + lo;
        if (mm) {
            if (tt) { npos++; spos += bce; }
            else {
                unsigned fx = (unsigned)__float2uint_rn(bce * FPSCALE);
                unsigned bin = fx >> FXSHIFT;
                if (bin >= NBINS) bin = NBINS - 1;   // tail guard (bce < 8 in data)
                atomicAdd(&hq[bin], (1ull << CSHIFT) | (unsigned long long)fx);
            }
        }
    };

    auto consume = [&](int s) {
        uint4 lv = stage[s][0][tid];   // ds_read_b128, 2-way bank alias (free)
        uint4 tv = stage[s][1][tid];
        uint4 mv = stage[s][2][tid];
        proc(lv.x, tv.x, mv.x);
        proc(lv.y, tv.y, mv.y);
        proc(lv.z, tv.z, mv.z);
        proc(lv.w, tv.w, mv.w);
    };

    issue(0, 0); issue(1, 1); issue(2, 2);       // 9 DMAs in flight

    int slot = 0;
    #pragma unroll 1
    for (int j = 0; j <= NT - 4; ++j) {
        WAITV(6); SCHED();       // tile j retired (oldest 3 of <=9)
        SBAR();                  // raw barrier: prefetched DMAs stay in flight
        consume(slot);
        SCHED();
        SBAR();                  // all waves done reading slot -> safe to overwrite
        issue(j + 3, slot);
        slot = (slot == NSLOT - 1) ? 0 : slot + 1;
    }
    WAITV(6); SCHED(); SBAR(); consume(slot); slot = (slot == NSLOT - 1) ? 0 : slot + 1;
    WAITV(3); SCHED(); SBAR(); consume(slot); slot = (slot == NSLOT - 1) ? 0 : slot + 1;
    WAITV(0); SCHED(); SBAR(); consume(slot);

    __syncthreads();   // vmcnt already 0; orders hq atomics for the flush

    // block-level reduce of npos/sumPos -> per-block partials
    for (int o = 32; o; o >>= 1) {
        npos += __shfl_down(npos, o);
        spos += __shfl_down(spos, o);
    }
    if ((tid & 63) == 0) { swp[tid >> 6] = npos; sws[tid >> 6] = (double)spos; }
    __syncthreads();
    if (tid == 0) {
        partNpos[blockIdx.x] = swp[0] + swp[1] + swp[2] + swp[3];
        partSpos[blockIdx.x] = sws[0] + sws[1] + sws[2] + sws[3];
    }

    // flush nonzero bins -> XCD-private hist copy
    const int r = blockIdx.x >> 6;               // BLOCKS_PER_ROW == 64
    unsigned long long* gh = hist + ((size_t)r * NCOPY + (blockIdx.x & (NCOPY - 1))) * NBINS;
    for (int b = tid; b < NBINS; b += 256) {
        unsigned long long v = hq[b];
        if (v) atomicAdd(&gh[b], v);
    }
}

// ---------- K2: per-row selection from packed hist + output ----------
__global__ __launch_bounds__(256) void k_final(
    const unsigned long long* __restrict__ hist,
    const unsigned* __restrict__ partNpos, const double* __restrict__ partSpos,
    float* __restrict__ out)
{
    __shared__ unsigned sc[2][256];
    __shared__ double   sd[2][256];
    __shared__ unsigned swp[4];
    __shared__ double   sws[4];
    __shared__ unsigned rcntgt, rcnt1;
    __shared__ double rsumgt, rsum1;

    const int r = blockIdx.x, tid = threadIdx.x;
    const unsigned long long* gh = hist + (size_t)r * NCOPY * NBINS;
    const double inv = 1.0 / (double)FPSCALE;

    // reduce per-block partials (BLOCKS_PER_ROW == 64 entries)
    {
        unsigned np = (tid < BLOCKS_PER_ROW) ? partNpos[r * BLOCKS_PER_ROW + tid] : 0u;
        double   sp = (tid < BLOCKS_PER_ROW) ? partSpos[r * BLOCKS_PER_ROW + tid] : 0.0;
        for (int o = 32; o; o >>= 1) { np += __shfl_down(np, o); sp += __shfl_down(sp, o); }
        if ((tid & 63) == 0) { swp[tid >> 6] = np; sws[tid >> 6] = sp; }
    }
    __syncthreads();
    const unsigned npos = swp[0] + swp[1] + swp[2] + swp[3];
    const double sumPos = sws[0] + sws[1] + sws[2] + sws[3];
    __syncthreads();

    // per-thread chunk of 4 bins (summed over the 8 copies), scanned high->low
    const int per = NBINS / 256;                 // 4
    const int b0 = NBINS - 1 - tid * per;
    unsigned lc[4]; double lsum[4];
    unsigned pc = 0; double ps = 0.0;
    #pragma unroll
    for (int i = 0; i < per; ++i) {
        unsigned long long v = 0ull;
        #pragma unroll
        for (int c = 0; c < NCOPY; ++c) v += gh[(size_t)c * NBINS + (b0 - i)];
        lc[i] = (unsigned)(v >> CSHIFT);
        lsum[i] = (double)(v & SUMMASK) * inv;
        pc += lc[i]; ps += lsum[i];
    }

    // inclusive Hillis-Steele scan (thread t covers bins >= NBINS - per*(t+1))
    int pp = 0;
    sc[0][tid] = pc; sd[0][tid] = ps;
    __syncthreads();
    for (int ofs = 1; ofs < 256; ofs <<= 1) {
        unsigned c = sc[pp][tid]; double s = sd[pp][tid];
        if (tid >= ofs) { c += sc[pp][tid - ofs]; s += sd[pp][tid - ofs]; }
        sc[pp ^ 1][tid] = c; sd[pp ^ 1][tid] = s;
        pp ^= 1;
        __syncthreads();
    }
    const unsigned nneg   = sc[pp][255];
    const double   sumNeg = sd[pp][255];

    long kl = (long)K_ALL - (long)npos;
    if (kl < 0) kl = 0;
    if (kl > (long)nneg) kl = (long)nneg;
    const unsigned Kneg = (unsigned)kl;

    double sum_sel = 0.0;
    if (Kneg >= nneg) {
        sum_sel = sumNeg;                        // keep-all (or Kneg==nneg==0)
    } else if (Kneg > 0) {
        // threshold bin: exactly one thread has exc < Kneg <= inc
        unsigned inc = sc[pp][tid];
        unsigned exc = inc - pc;
        double   exs = sd[pp][tid] - ps;
        if (exc < Kneg && Kneg <= inc) {
            unsigned cum = exc; double csum = exs;
            #pragma unroll
            for (int i = 0; i < per; ++i) {
                if (cum + lc[i] >= Kneg) {
                    rcntgt = cum; rsumgt = csum;
                    rcnt1 = lc[i]; rsum1 = lsum[i];        // stash: no re-read
                    break;
                }
                cum += lc[i]; csum += lsum[i];
            }
        }
        __syncthreads();
        if (tid == 0) {
            const unsigned cntT1 = rcnt1;
            const double   sumT1 = rsum1;
            const unsigned Kp = Kneg - rcntgt;   // 1..cntT1
            const double w = 1.0 / 128.0;        // bin width
            const double avg = sumT1 / (double)cntT1;
            // shifted-uniform top-Kp mean; exact when Kp == cntT1
            const double topmean = avg + 0.5 * w * (1.0 - (double)Kp / (double)cntT1);
            sum_sel = rsumgt + (double)Kp * topmean;
        }
    }

    if (tid == 0) {
        unsigned long long kk = (unsigned long long)npos + (unsigned long long)Kneg;
        double per_s = 0.0;
        if (kk > 0) per_s = (sumPos + sum_sel) / (double)kk;
        // kk==0 => no tissue => reference falls back to loss[:,0] == 0
        atomicAdd(out, (float)(per_s / (double)B_ROWS));
    }
}

// ---------- launch ----------
extern "C" void kernel_launch(void* const* d_in, const int* in_sizes, int n_in,
                              void* d_out, int out_size, void* d_ws, size_t ws_size,
                              hipStream_t stream)
{
    const float* logits = (const float*)d_in[0];
    const int*   targets = (const int*)d_in[1];
    const int*   tissue = (const int*)d_in[2];

    char* ws = (char*)d_ws;
    size_t off = 0;
    // zeroed region: packed hist copies (at ws start)
    unsigned long long* hist = (unsigned long long*)(ws + off);
    off += (size_t)B_ROWS * NCOPY * NBINS * 8;   // 512 KB
    size_t zero_size = off;
    // non-zeroed partials (every slot written before read)
    unsigned* partNpos = (unsigned*)(ws + off); off += (size_t)NBLK1 * 4;
    double*   partSpos = (double*)(ws + off);   off += (size_t)NBLK1 * 8;

    hipMemsetAsync(ws, 0, zero_size, stream);

    k_pass1<<<NBLK1, 256, 0, stream>>>(
        logits, targets, tissue, hist, partNpos, partSpos, (float*)d_out);
    k_final<<<B_ROWS, 256, 0, stream>>>(hist, partNpos, partSpos, (float*)d_out);
}

// Round 8
// 121.743 us; speedup vs baseline: 1.0903x; 1.0297x over previous
//
#include <hip/hip_runtime.h>
#include <cstdint>
#include <cstddef>

// Problem constants (B=8, H=W=1024)
#define N_PIX   1048576
#define B_ROWS  8
#define K_ALL   524288          // max(1, int(N*0.5))
#define BLOCKS_PER_ROW 128      // pass1 blocks per row (1024 total, 4/CU persistent)
#define NSTAGE  8               // quads per thread, software-pipelined
#define NBINS   1024            // linear bins, width 1/128 on [0,8)
#define FXSHIFT 11              // bin = fx >> 11 (2^18 fixed-point -> 128 bins/unit)
#define NCOPY   8               // hist copies (XCD-private under round-robin dispatch)
#define CSHIFT  42              // u64 = (count << 42) | fixed_sum(2^-18)
#define SUMMASK ((1ull << CSHIFT) - 1ull)
#define FPSCALE 262144.0f       // 2^18 fixed-point scale for packed sums

// FINAL (R8): best-of-session structure (R5, 121.2us, absmax 0.0).
// Session elimination matrix: 7 structurally disjoint pass1 variants
// (reg-burst / pinned / barrier-reorder / persistent-pipelined / pure-stream
// no-LDS-no-atomics / 3-kernel split / global_load_lds DMA ring) ALL land at
// 38-42us for ~96MB of reads with NO counter >20%. Explanation: the harness's
// 2x256MiB poison fills run at 80-83% HBM peak (roofline) and partially land
// DIRTY in the 256MiB Infinity Cache (fill rows with 256MiB written but ~15KB
// HBM traffic); the ~41us L3->HBM writeback drain overlaps our window and
// caps our read bandwidth at ~1.3-2.3 TB/s. Environmental; not addressable
// from kernel structure. Chain floor therefore ~41us; total ~121us.
// R1 lesson stands: no single-kernel fusion (threadfence = L2 wb storm).

// ---------- K1: loss + packed count/sum LDS hist + per-block npos/sumPos ----------
__global__ __launch_bounds__(256) void k_pass1(
    const float4* __restrict__ lg, const int4* __restrict__ tg, const int4* __restrict__ mk,
    unsigned long long* __restrict__ hist,
    unsigned* __restrict__ partNpos, double* __restrict__ partSpos, float* __restrict__ out)
{
    __shared__ unsigned long long hq[NBINS];   // 8 KB
    __shared__ unsigned swp[4];
    __shared__ double   sws[4];
    const int tid = threadIdx.x;

    // LDS init FIRST; this barrier drains only ds_writes (cheap)
    for (int b = tid; b < NBINS; b += 256) hq[b] = 0ull;
    if (blockIdx.x == 0 && tid == 0) *out = 0.f;   // k_final (later dispatch) accumulates
    __syncthreads();
    __builtin_amdgcn_sched_barrier(0);   // loads must not hoist above the barrier

    const int r = blockIdx.x >> 7;                          // BLOCKS_PER_ROW == 128
    const size_t qbase = (size_t)blockIdx.x * (NSTAGE * 256) + tid;

    unsigned npos = 0; float spos = 0.f;

    auto proc = [&](float xx, int tt, int mm) {
        float ax = fabsf(xx);
        float e = __expf(-ax);
        float l = __logf(1.f + e);
        float bce = fmaxf(xx, 0.f) - xx * (float)tt + l;
        if (mm) {
            if (tt) { npos++; spos += bce; }
            else {
                unsigned fx = (unsigned)__float2uint_rn(bce * FPSCALE);
                unsigned bin = fx >> FXSHIFT;
                if (bin >= NBINS) bin = NBINS - 1;          // tail guard (bce<8 in data)
                atomicAdd(&hq[bin], (1ull << CSHIFT) | (unsigned long long)fx);
            }
        }
    };

    // depth-1 software pipeline over NSTAGE stages; x/t/m indexed only by
    // compile-time constants (full unroll) -> stays in registers (rule #20)
    float4 x[2]; int4 t[2]; int4 m[2];
    x[0] = lg[qbase]; t[0] = tg[qbase]; m[0] = mk[qbase];
    #pragma unroll
    for (int j = 0; j < NSTAGE; ++j) {
        const int cur = j & 1, nxt = cur ^ 1;
        if (j < NSTAGE - 1) {
            const size_t q = qbase + (size_t)(j + 1) * 256;
            x[nxt] = lg[q]; t[nxt] = tg[q]; m[nxt] = mk[q];
        }
        __builtin_amdgcn_sched_barrier(0);   // loads stay above, compute below
        proc(x[cur].x, t[cur].x, m[cur].x);
        proc(x[cur].y, t[cur].y, m[cur].y);
        proc(x[cur].z, t[cur].z, m[cur].z);
        proc(x[cur].w, t[cur].w, m[cur].w);
        __builtin_amdgcn_sched_barrier(0);   // keep stages separated
    }

    // block-level reduce of npos/sumPos -> per-block partials
    for (int o = 32; o; o >>= 1) {
        npos += __shfl_down(npos, o);
        spos += __shfl_down(spos, o);
    }
    if ((tid & 63) == 0) { swp[tid >> 6] = npos; sws[tid >> 6] = (double)spos; }
    __syncthreads();   // also makes hq atomics visible for the flush
    if (tid == 0) {
        partNpos[blockIdx.x] = swp[0] + swp[1] + swp[2] + swp[3];
        partSpos[blockIdx.x] = sws[0] + sws[1] + sws[2] + sws[3];
    }

    // flush nonzero bins -> XCD-private hist copy (one u64 atomic per occupied bin)
    unsigned long long* gh = hist + ((size_t)r * NCOPY + (blockIdx.x & (NCOPY - 1))) * NBINS;
    for (int b = tid; b < NBINS; b += 256) {
        unsigned long long v = hq[b];
        if (v) atomicAdd(&gh[b], v);
    }
}

// ---------- K2: per-row selection from packed hist + output ----------
__global__ __launch_bounds__(256) void k_final(
    const unsigned long long* __restrict__ hist,
    const unsigned* __restrict__ partNpos, const double* __restrict__ partSpos,
    float* __restrict__ out)
{
    __shared__ unsigned sc[2][256];
    __shared__ double   sd[2][256];
    __shared__ unsigned swp[4];
    __shared__ double   sws[4];
    __shared__ unsigned rcntgt, rcnt1;
    __shared__ double rsumgt, rsum1;

    const int r = blockIdx.x, tid = threadIdx.x;
    const unsigned long long* gh = hist + (size_t)r * NCOPY * NBINS;
    const double inv = 1.0 / (double)FPSCALE;

    // reduce per-block partials (BLOCKS_PER_ROW == 128 entries)
    {
        unsigned np = (tid < BLOCKS_PER_ROW) ? partNpos[r * BLOCKS_PER_ROW + tid] : 0u;
        double   sp = (tid < BLOCKS_PER_ROW) ? partSpos[r * BLOCKS_PER_ROW + tid] : 0.0;
        for (int o = 32; o; o >>= 1) { np += __shfl_down(np, o); sp += __shfl_down(sp, o); }
        if ((tid & 63) == 0) { swp[tid >> 6] = np; sws[tid >> 6] = sp; }
    }
    __syncthreads();
    const unsigned npos = swp[0] + swp[1] + swp[2] + swp[3];
    const double sumPos = sws[0] + sws[1] + sws[2] + sws[3];
    __syncthreads();

    // per-thread chunk of 4 bins (summed over the 8 copies), scanned high->low
    const int per = NBINS / 256;                 // 4
    const int b0 = NBINS - 1 - tid * per;
    unsigned lc[4]; double lsum[4];
    unsigned pc = 0; double ps = 0.0;
    #pragma unroll
    for (int i = 0; i < per; ++i) {
        unsigned long long v = 0ull;
        #pragma unroll
        for (int c = 0; c < NCOPY; ++c) v += gh[(size_t)c * NBINS + (b0 - i)];
        lc[i] = (unsigned)(v >> CSHIFT);
        lsum[i] = (double)(v & SUMMASK) * inv;
        pc += lc[i]; ps += lsum[i];
    }

    // inclusive Hillis-Steele scan (thread t covers bins >= NBINS - per*(t+1))
    int pp = 0;
    sc[0][tid] = pc; sd[0][tid] = ps;
    __syncthreads();
    for (int ofs = 1; ofs < 256; ofs <<= 1) {
        unsigned c = sc[pp][tid]; double s = sd[pp][tid];
        if (tid >= ofs) { c += sc[pp][tid - ofs]; s += sd[pp][tid - ofs]; }
        sc[pp ^ 1][tid] = c; sd[pp ^ 1][tid] = s;
        pp ^= 1;
        __syncthreads();
    }
    const unsigned nneg   = sc[pp][255];
    const double   sumNeg = sd[pp][255];

    long kl = (long)K_ALL - (long)npos;
    if (kl < 0) kl = 0;
    if (kl > (long)nneg) kl = (long)nneg;
    const unsigned Kneg = (unsigned)kl;

    double sum_sel = 0.0;
    if (Kneg >= nneg) {
        sum_sel = sumNeg;                        // keep-all (or Kneg==nneg==0)
    } else if (Kneg > 0) {
        // threshold bin: exactly one thread has exc < Kneg <= inc
        unsigned inc = sc[pp][tid];
        unsigned exc = inc - pc;
        double   exs = sd[pp][tid] - ps;
        if (exc < Kneg && Kneg <= inc) {
            unsigned cum = exc; double csum = exs;
            #pragma unroll
            for (int i = 0; i < per; ++i) {
                if (cum + lc[i] >= Kneg) {
                    rcntgt = cum; rsumgt = csum;
                    rcnt1 = lc[i]; rsum1 = lsum[i];        // stash: no re-read needed
                    break;
                }
                cum += lc[i]; csum += lsum[i];
            }
        }
        __syncthreads();
        if (tid == 0) {
            const unsigned cntT1 = rcnt1;
            const double   sumT1 = rsum1;
            const unsigned Kp = Kneg - rcntgt;   // 1..cntT1
            const double w = 1.0 / 128.0;        // bin width
            const double avg = sumT1 / (double)cntT1;
            // shifted-uniform top-Kp mean; exact when Kp == cntT1
            const double topmean = avg + 0.5 * w * (1.0 - (double)Kp / (double)cntT1);
            sum_sel = rsumgt + (double)Kp * topmean;
        }
    }

    if (tid == 0) {
        unsigned long long kk = (unsigned long long)npos + (unsigned long long)Kneg;
        double per_s = 0.0;
        if (kk > 0) per_s = (sumPos + sum_sel) / (double)kk;
        // kk==0 => no tissue => reference falls back to loss[:,0] == 0
        atomicAdd(out, (float)(per_s / (double)B_ROWS));
    }
}

// ---------- launch ----------
extern "C" void kernel_launch(void* const* d_in, const int* in_sizes, int n_in,
                              void* d_out, int out_size, void* d_ws, size_t ws_size,
                              hipStream_t stream)
{
    const float* logits = (const float*)d_in[0];
    const int*   targets = (const int*)d_in[1];
    const int*   tissue = (const int*)d_in[2];

    const int NBLK = B_ROWS * BLOCKS_PER_ROW;   // 1024
    char* ws = (char*)d_ws;
    size_t off = 0;
    // zeroed region: packed hist copies (at ws start)
    unsigned long long* hist = (unsigned long long*)(ws + off);
    off += (size_t)B_ROWS * NCOPY * NBINS * 8;   // 512 KB
    size_t zero_size = off;
    // non-zeroed partials (every slot written before read)
    unsigned* partNpos = (unsigned*)(ws + off); off += (size_t)NBLK * 4;
    double*   partSpos = (double*)(ws + off);   off += (size_t)NBLK * 8;

    hipMemsetAsync(ws, 0, zero_size, stream);

    k_pass1<<<NBLK, 256, 0, stream>>>(
        (const float4*)logits, (const int4*)targets, (const int4*)tissue,
        hist, partNpos, partSpos, (float*)d_out);
    k_final<<<B_ROWS, 256, 0, stream>>>(hist, partNpos, partSpos, (float*)d_out);
}